// Round 4
// baseline (5354.510 us; speedup 1.0000x reference)
//
#include <hip/hip_runtime.h>
#include <hip/hip_cooperative_groups.h>
#include <math.h>

namespace cg = cooperative_groups;

#define NDATA   20000
#define DFEAT   1024
#define TWO_M   64
#define MM      32
#define ETA_F   1e-4f
#define THRES_F 1e-12f
#define NSWEEP  10
#define NBLK    256
#define NTHR    1024
#define NWAVES  (NBLK * (NTHR / 64))

// d_ws layout (bytes):
//   0      : int ctl[8]   (ring slots 0..3, [4]=rc after shrink)  -- memset 0x7F by host
//   256    : float Bt[64*1024]      columns of B (row j = col j), 256 KB
//   262400 : int   ttime[64]        trigger time of column j
//   262656 : float base[20000]      scalar at segment start (post-shrink snapshot)
//   342656 : float scv[20000]       current scalar (valid where flag=1)
//   422656 : int   flag[20000]      1 = still a possible trigger

__device__ __forceinline__ float wave_sum(float v) {
    v += __shfl_xor(v, 1);  v += __shfl_xor(v, 2);  v += __shfl_xor(v, 4);
    v += __shfl_xor(v, 8);  v += __shfl_xor(v, 16); v += __shfl_xor(v, 32);
    return v;
}
__device__ __forceinline__ int wave_min_i(int v) {
    v = min(v, __shfl_xor(v, 1));  v = min(v, __shfl_xor(v, 2));
    v = min(v, __shfl_xor(v, 4));  v = min(v, __shfl_xor(v, 8));
    v = min(v, __shfl_xor(v, 16)); v = min(v, __shfl_xor(v, 32));
    return v;
}
__device__ __forceinline__ void pair_from(int p, int &a, int &b) {
    int a_ = 0, rem = p;
    while (rem >= 64 - a_) { rem -= 64 - a_; ++a_; }
    a = a_; b = a_ + rem;
}
__device__ __forceinline__ float dot16(float4 x0, float4 x1, float4 x2, float4 x3,
                                       float4 y0, float4 y1, float4 y2, float4 y3) {
    float d = x0.x*y0.x + x0.y*y0.y + x0.z*y0.z + x0.w*y0.w;
    d += x1.x*y1.x + x1.y*y1.y + x1.z*y1.z + x1.w*y1.w;
    d += x2.x*y2.x + x2.y*y2.y + x2.z*y2.z + x2.w*y2.w;
    d += x3.x*y3.x + x3.y*y3.y + x3.z*y3.z + x3.w*y3.w;
    return d;
}

// out[t] = base[t] + sum over segment cols j in [jlo,jhi] with ttime[j] < t of (Bt_j . alpha_t)^2
__device__ void finalize_range(const float* __restrict__ A,
                               const float* __restrict__ base,
                               const float* __restrict__ Bt,
                               const int* __restrict__ ttime,
                               float* __restrict__ out,
                               int lo, int hi, int jlo, int jhi,
                               int gwave, int lane)
{
    for (int t = lo + gwave; t <= hi; t += NWAVES) {
        const float4* At = (const float4*)(A + (size_t)t * DFEAT);
        float4 a0 = At[lane*4+0], a1 = At[lane*4+1], a2 = At[lane*4+2], a3 = At[lane*4+3];
        float o = base[t];
        for (int jc = jlo; jc <= jhi; ++jc) {
            if (ttime[jc] >= t) break;          // times ascending in jc
            const float4* Bj = (const float4*)(Bt + (size_t)jc * DFEAT);
            float d = dot16(a0, a1, a2, a3,
                            Bj[lane*4+0], Bj[lane*4+1], Bj[lane*4+2], Bj[lane*4+3]);
            d = wave_sum(d);
            o += d * d;
        }
        if (lane == 0) out[t] = o;
    }
}

__global__ __launch_bounds__(NTHR, 4)
void sftrl_coop2(const float* __restrict__ A,
                 const float* __restrict__ Y,
                 float* __restrict__ out,
                 int* __restrict__ ctl,
                 float* __restrict__ Bt,
                 int* __restrict__ ttime,
                 float* __restrict__ base,
                 float* __restrict__ scv,
                 int* __restrict__ flag)
{
    cg::grid_group grid = cg::this_grid();
    const int tid   = threadIdx.x;
    const int lane  = tid & 63;
    const int gwave = blockIdx.x * (NTHR / 64) + (tid >> 6);
    const bool blk0 = (blockIdx.x == 0);

    __shared__ int   s_min;
    // shrink-only LDS (block 0)
    __shared__ float tg[64 * 257];
    __shared__ float s_G[2][4096];
    __shared__ float s_U[2][4096];
    __shared__ float s_rotA[64], s_rotB[64];
    __shared__ int   s_prt[64];
    __shared__ float s_S[64], s_Ss[64];
    __shared__ int   s_perm[64];
    __shared__ int   s_misc[2];

    // ---------------- INIT ----------------
    int tmin = NDATA;
    for (int i = blockIdx.x * NTHR + tid; i < NDATA; i += NBLK * NTHR) {
        base[i] = 0.f;
        scv[i]  = 0.f;
        int f = (0.f <= Y[i]) ? 1 : 0;          // scalar starts at 0
        flag[i] = f;
        if (f && i < tmin) tmin = i;
    }
    for (int i = blockIdx.x * NTHR + tid; i < TWO_M * DFEAT; i += NBLK * NTHR) Bt[i] = 0.f;
    tmin = wave_min_i(tmin);
    if (tid == 0) s_min = NDATA;
    __syncthreads();
    if (lane == 0) atomicMin(&s_min, tmin);
    __syncthreads();
    if (tid == 0 && s_min < NDATA) atomicMin(&ctl[0], s_min);   // slots preset to 0x7F7F7F7F
    __threadfence();
    grid.sync();

    // ---------------- main trigger loop ----------------
    int rc = 0, it = 0, fin_hi = -1, seg_lo = 1;

    for (;;) {
        const int rslot = it & 3;
        const int wslot = (it + 1) & 3;
        const int zslot = (it + 2) & 3;

        int ts = ctl[rslot];
        if (ts >= NDATA) {
            // no more triggers: finalize the open segment and exit
            finalize_range(A, base, Bt, ttime, out, fin_hi + 1, NDATA - 1,
                           seg_lo, rc, gwave, lane);
            break;
        }

        float scst = scv[ts];
        float bst  = Y[ts];
        float kap  = sqrtf(2.f * ETA_F * (bst - scst));
        rc += 1;
        if (blk0) {                               // append column rc
            Bt[(size_t)rc * DFEAT + tid] = kap * A[(size_t)ts * DFEAT + tid];
            if (tid == 0) ttime[rc] = ts;
        }

        if (rc == TWO_M - 1) {
            // ============ SHRINK path (statistically unreachable, kept correct) ============
            // 1) finalize closing segment (cols seg_lo..rc-1; col rc time==ts excluded anyway)
            finalize_range(A, base, Bt, ttime, out, fin_hi + 1, ts,
                           seg_lo, rc - 1, gwave, lane);
            __threadfence();
            grid.sync();                          // Bt stable before rewrite

            // 2) block-0 Jacobi eigen-shrink of Gram(Bt)
            if (blk0) {
                float acc0 = 0.f, acc1 = 0.f, acc2 = 0.f;
                int a0i, b0i, a1i, b1i, a2i, b2i;
                pair_from(tid, a0i, b0i);
                pair_from(tid + 1024, a1i, b1i);
                pair_from((tid < 32) ? (tid + 2048) : 0, a2i, b2i);
                for (int c = 0; c < 4; ++c) {
                    __syncthreads();
                    for (int q = tid; q < 64 * 64; q += NTHR) {
                        int jj = q >> 6, d4 = q & 63;
                        float4 v = ((const float4*)(Bt + (size_t)jj * DFEAT + c * 256))[d4];
                        tg[jj * 257 + d4 * 4 + 0] = v.x;
                        tg[jj * 257 + d4 * 4 + 1] = v.y;
                        tg[jj * 257 + d4 * 4 + 2] = v.z;
                        tg[jj * 257 + d4 * 4 + 3] = v.w;
                    }
                    __syncthreads();
                    for (int dd = 0; dd < 256; ++dd) {
                        acc0 += tg[a0i * 257 + dd] * tg[b0i * 257 + dd];
                        acc1 += tg[a1i * 257 + dd] * tg[b1i * 257 + dd];
                        acc2 += tg[a2i * 257 + dd] * tg[b2i * 257 + dd];
                    }
                }
                s_G[0][a0i * 64 + b0i] = acc0; s_G[0][b0i * 64 + a0i] = acc0;
                s_G[0][a1i * 64 + b1i] = acc1; s_G[0][b1i * 64 + a1i] = acc1;
                if (tid < 32) { s_G[0][a2i * 64 + b2i] = acc2; s_G[0][b2i * 64 + a2i] = acc2; }
                for (int e4 = 0; e4 < 4; ++e4) {
                    int e = tid + e4 * 1024;
                    s_U[0][e] = ((e >> 6) == (e & 63)) ? 1.f : 0.f;
                }
                __syncthreads();

                int cur = 0;
                for (int sw = 0; sw < NSWEEP; ++sw) {
                    for (int r = 0; r < 63; ++r) {
                        if (tid < 32) {
                            int p_, q_;
                            if (tid == 0) { p_ = 63; q_ = r; }
                            else { p_ = (r + tid) % 63; q_ = (r + 63 - tid) % 63; }
                            float gpp = s_G[cur][p_ * 64 + p_];
                            float gqq = s_G[cur][q_ * 64 + q_];
                            float gpq = s_G[cur][p_ * 64 + q_];
                            float cc = 1.f, sn = 0.f;
                            if (fabsf(gpq) > 1e-20f) {
                                float tau = (gqq - gpp) / (2.f * gpq);
                                float tt  = (tau >= 0.f ? 1.f : -1.f) /
                                            (fabsf(tau) + sqrtf(1.f + tau * tau));
                                cc = 1.f / sqrtf(1.f + tt * tt);
                                sn = tt * cc;
                            }
                            s_rotA[p_] = cc; s_rotB[p_] = -sn; s_prt[p_] = q_;
                            s_rotA[q_] = cc; s_rotB[q_] = sn;  s_prt[q_] = p_;
                        }
                        __syncthreads();
                        float ng[4], nu[4];
                        for (int e4 = 0; e4 < 4; ++e4) {
                            int e = tid + e4 * 1024;
                            int row = e >> 6, col = e & 63;
                            int pr = s_prt[row], pc = s_prt[col];
                            float ar = s_rotA[row], br = s_rotB[row];
                            float ac = s_rotA[col], bc = s_rotB[col];
                            ng[e4] = ar * ac * s_G[cur][row * 64 + col]
                                   + br * ac * s_G[cur][pr * 64 + col]
                                   + ar * bc * s_G[cur][row * 64 + pc]
                                   + br * bc * s_G[cur][pr * 64 + pc];
                            nu[e4] = ac * s_U[cur][row * 64 + col]
                                   + bc * s_U[cur][row * 64 + pc];
                        }
                        for (int e4 = 0; e4 < 4; ++e4) {
                            int e = tid + e4 * 1024;
                            s_G[cur ^ 1][e] = ng[e4];
                            s_U[cur ^ 1][e] = nu[e4];
                        }
                        __syncthreads();
                        cur ^= 1;
                    }
                }

                if (tid < 64) {
                    float lam = s_G[cur][tid * 64 + tid];
                    if (lam <= THRES_F) lam = 0.f;
                    s_S[tid] = lam;
                }
                __syncthreads();
                if (tid < 64) {
                    float my = s_S[tid];
                    int rank = 0;
                    for (int i = 0; i < 64; ++i) {
                        float o = s_S[i];
                        rank += ((o > my) || (o == my && i < tid)) ? 1 : 0;
                    }
                    s_perm[rank] = tid;
                    s_Ss[rank]   = my;
                }
                __syncthreads();
                if (tid == 0) {
                    int nz = 0;
                    for (int i = 0; i < 64; ++i) nz += (s_Ss[i] > 0.f) ? 1 : 0;
                    s_misc[0] = nz;
                    s_misc[1] = (nz >= MM) ? 1 : 0;
                }
                __syncthreads();
                const int   nnz = s_misc[0];
                const int   ge  = s_misc[1];
                const float S32 = s_Ss[MM];

                for (int e4 = 0; e4 < 4; ++e4) {
                    int e = tid + e4 * 1024;
                    int kk = e >> 6, jn = e & 63;
                    float Sj = s_Ss[jn];
                    float f;
                    if (ge) f = (jn < MM - 1 && Sj > 0.f)
                                  ? sqrtf(fmaxf(Sj - S32, 0.f) / Sj) : 0.f;
                    else    f = (jn < nnz) ? 1.f : 0.f;
                    s_G[0][kk * 64 + jn] = s_U[cur][kk * 64 + s_perm[jn]] * f;
                }
                __syncthreads();

                for (int c = 0; c < 4; ++c) {
                    __syncthreads();
                    for (int q = tid; q < 64 * 64; q += NTHR) {
                        int jj = q >> 6, d4 = q & 63;
                        float4 v = ((const float4*)(Bt + (size_t)jj * DFEAT + c * 256))[d4];
                        tg[jj * 257 + d4 * 4 + 0] = v.x;
                        tg[jj * 257 + d4 * 4 + 1] = v.y;
                        tg[jj * 257 + d4 * 4 + 2] = v.z;
                        tg[jj * 257 + d4 * 4 + 3] = v.w;
                    }
                    __syncthreads();
                    for (int q = tid; q < 64 * 256; q += NTHR) {
                        int dd = q & 255, jn = q >> 8;
                        float sum = 0.f;
                        for (int kk = 0; kk < 64; ++kk)
                            sum += tg[kk * 257 + dd] * s_G[0][kk * 64 + jn];
                        Bt[(size_t)jn * DFEAT + c * 256 + dd] = sum;
                    }
                }
                __syncthreads();
                if (tid == 0) ctl[4] = ge ? (MM - 1) : nnz;
            }
            if (blk0 && tid == 0) ctl[zslot] = NDATA;     // ring reset
            __threadfence();
            grid.sync();                          // B_new + ctl[4] visible

            int rcn = ctl[4];
            // 3) recompute pass: rebuild base/scv/flag for t > ts, find next trigger
            if (tid == 0) s_min = NDATA;
            __syncthreads();
            int wmin = NDATA;
            for (int tq = ts + 1 + gwave; tq < NDATA; tq += NWAVES) {
                const float4* At = (const float4*)(A + (size_t)tq * DFEAT);
                float4 a0 = At[lane*4+0], a1 = At[lane*4+1];
                float4 a2 = At[lane*4+2], a3 = At[lane*4+3];
                float sc = 0.f;
                for (int jc = 0; jc < TWO_M; ++jc) {
                    const float4* Bj = (const float4*)(Bt + (size_t)jc * DFEAT);
                    float d = dot16(a0, a1, a2, a3,
                                    Bj[lane*4+0], Bj[lane*4+1], Bj[lane*4+2], Bj[lane*4+3]);
                    d = wave_sum(d);
                    sc += d * d;
                }
                float b = Y[tq];
                int f = (sc <= b) ? 1 : 0;
                if (lane == 0) { base[tq] = sc; scv[tq] = sc; flag[tq] = f; }
                if (f) wmin = min(wmin, tq);
            }
            if (lane == 0) atomicMin(&s_min, wmin);
            __syncthreads();
            if (tid == 0 && s_min < NDATA) atomicMin(&ctl[wslot], s_min);
            __threadfence();
            grid.sync();

            rc = rcn; seg_lo = rc + 1; fin_hi = ts; it += 1;
            continue;
            // ============ end SHRINK path ============
        }

        // ---- correction pass: flagged rows only; scv += (kap * a_ts . a_t)^2 ----
        if (tid == 0) s_min = NDATA;
        __syncthreads();
        const float4* Ast = (const float4*)(A + (size_t)ts * DFEAT);
        float4 as0 = Ast[lane*4+0], as1 = Ast[lane*4+1];
        float4 as2 = Ast[lane*4+2], as3 = Ast[lane*4+3];
        int wmin = NDATA;
        for (int tq = ts + 1 + gwave; tq < NDATA; tq += NWAVES) {
            if (!flag[tq]) continue;
            const float4* At = (const float4*)(A + (size_t)tq * DFEAT);
            float4 a0 = At[lane*4+0], a1 = At[lane*4+1];
            float4 a2 = At[lane*4+2], a3 = At[lane*4+3];
            float d = dot16(as0, as1, as2, as3, a0, a1, a2, a3);
            d = wave_sum(d);
            float v  = kap * d;
            float sc = scv[tq] + v * v;
            if (sc <= Y[tq]) {
                if (lane == 0) scv[tq] = sc;      // stays a candidate
                wmin = min(wmin, tq);
            } else {
                if (lane == 0) flag[tq] = 0;      // monotone: can never trigger again
            }
        }
        if (lane == 0) atomicMin(&s_min, wmin);
        __syncthreads();
        if (tid == 0 && s_min < NDATA) atomicMin(&ctl[wslot], s_min);
        if (blk0 && tid == 0) ctl[zslot] = NDATA; // ring reset (last read >=2 syncs ago)
        __threadfence();
        grid.sync();

        it += 1;
    }
}

extern "C" void kernel_launch(void* const* d_in, const int* in_sizes, int n_in,
                              void* d_out, int out_size, void* d_ws, size_t ws_size,
                              hipStream_t stream) {
    (void)in_sizes; (void)n_in; (void)ws_size; (void)out_size;
    const float* A = (const float*)d_in[0];
    const float* Y = (const float*)d_in[1];
    float* out  = (float*)d_out;
    char*  ws   = (char*)d_ws;
    int*   ctl   = (int*)ws;
    float* Bt    = (float*)(ws + 256);
    int*   ttime = (int*)(ws + 262400);
    float* base  = (float*)(ws + 262656);
    float* scv   = (float*)(ws + 342656);
    int*   flag  = (int*)(ws + 422656);

    // preset ring slots to +large (0x7F7F7F7F) so atomicMin works from poisoned ws
    hipMemsetAsync(ctl, 0x7F, 8 * sizeof(int), stream);

    void* kargs[] = { (void*)&A, (void*)&Y, (void*)&out, (void*)&ctl,
                      (void*)&Bt, (void*)&ttime, (void*)&base, (void*)&scv, (void*)&flag };
    hipLaunchCooperativeKernel((void*)sftrl_coop2, dim3(NBLK), dim3(NTHR),
                               kargs, 0, stream);
}

// Round 5
// 1506.837 us; speedup vs baseline: 3.5535x; 3.5535x over previous
//
#include <hip/hip_runtime.h>
#include <hip/hip_cooperative_groups.h>
#include <math.h>

namespace cg = cooperative_groups;

#define NDATA   20000
#define DFEAT   1024
#define TWO_M   64
#define MM      32
#define ETA_F   1e-4f
#define THRES_F 1e-12f
#define NSWEEP  8
#define NBLK    256
#define NTHR    1024
#define NW      (NBLK*(NTHR/64))
#define CH      384
#define BIGF    3.0e38f

// ---- ws layout (bytes) ----
#define O_CTL    0         // int[16]
#define O_CNT    256       // int[256]
#define O_ACCT   1280      // int[64]
#define O_ACCK   1536      // float[64]
#define O_TTIME  1792      // int[64]
#define O_BT     2048      // float[64*1024]
#define O_BASE   264192    // float[20000]
#define O_SCV    344192    // float[20000]
#define O_FLAG   424192    // int[20000]
#define O_CL0    504192    // int[20000]
#define O_LA     584192    // int[20000]
#define O_LB     664192    // int[20000]
#define O_CHT    744192    // int[CH]
#define O_CHB    746240    // float[CH]
#define O_CHS    748288    // float[CH]
#define O_D      750336    // float[CH*CH]  (589824 B) -> total ~1.34 MB

#define C_NACC 0
#define C_RC   1
#define C_SHR  2
#define C_TS   3
#define C_RCA  4
#define C_DONE 5

// jacobi LDS mapping inside SH[32832]
#define TG(r,c)     SH[(r)*257 + (c)]
#define SG(cb,idx)  SH[16448 + (cb)*4096 + (idx)]
#define SU(cb,idx)  SH[24640 + (cb)*4096 + (idx)]

__device__ __forceinline__ float wave_sum(float v) {
    v += __shfl_xor(v, 1);  v += __shfl_xor(v, 2);  v += __shfl_xor(v, 4);
    v += __shfl_xor(v, 8);  v += __shfl_xor(v, 16); v += __shfl_xor(v, 32);
    return v;
}
__device__ __forceinline__ int wave_min_i(int v) {
    v = min(v, __shfl_xor(v, 1));  v = min(v, __shfl_xor(v, 2));
    v = min(v, __shfl_xor(v, 4));  v = min(v, __shfl_xor(v, 8));
    v = min(v, __shfl_xor(v, 16)); v = min(v, __shfl_xor(v, 32));
    return v;
}
__device__ __forceinline__ void pair_from(int p, int &a, int &b) {
    int a_ = 0, rem = p;
    while (rem >= 64 - a_) { rem -= 64 - a_; ++a_; }
    a = a_; b = a_ + rem;
}
__device__ __forceinline__ float dot16(float4 x0, float4 x1, float4 x2, float4 x3,
                                       float4 y0, float4 y1, float4 y2, float4 y3) {
    float d = x0.x*y0.x + x0.y*y0.y + x0.z*y0.z + x0.w*y0.w;
    d += x1.x*y1.x + x1.y*y1.y + x1.z*y1.z + x1.w*y1.w;
    d += x2.x*y2.x + x2.y*y2.y + x2.z*y2.z + x2.w*y2.w;
    d += x3.x*y3.x + x3.y*y3.y + x3.z*y3.z + x3.w*y3.w;
    return d;
}
__device__ __forceinline__ int lbound(const int* arr, int n, int key) {
    int lo = 0, hi = n;
    while (lo < hi) { int mid = (lo + hi) >> 1; if (arr[mid] > key) hi = mid; else lo = mid + 1; }
    return lo;
}

// out[t] = base[t] + sum_{j in [jlo,jhi], ttime[j] < t} (Bt_j . alpha_t)^2
__device__ void finalize_range(const float* __restrict__ A, const float* __restrict__ base,
                               const float* __restrict__ Bt, const int* __restrict__ ttime,
                               float* __restrict__ out,
                               int lo, int hi, int jlo, int jhi, int gw, int lane)
{
    for (int t = lo + gw; t <= hi; t += NW) {
        const float4* At = (const float4*)(A + (size_t)t * DFEAT);
        float4 a0 = At[lane*4+0], a1 = At[lane*4+1], a2 = At[lane*4+2], a3 = At[lane*4+3];
        float o = base[t];
        for (int jc = jlo; jc <= jhi; ++jc) {
            if (ttime[jc] >= t) break;                 // ttimes ascending within segment
            const float4* Bj = (const float4*)(Bt + (size_t)jc * DFEAT);
            float d = dot16(a0, a1, a2, a3,
                            Bj[lane*4+0], Bj[lane*4+1], Bj[lane*4+2], Bj[lane*4+3]);
            d = wave_sum(d);
            o += d * d;
        }
        if (lane == 0) out[t] = o;
    }
}

// pairwise dots of chunk rows: D[i*CH+j] = alpha_{list[i]} . alpha_{list[j]}, j > i
__device__ void build_D(const float* __restrict__ A, const int* __restrict__ listP,
                        int clen, float* __restrict__ D, int w, int lane)
{
    if (w >= CH * 8) return;
    int i  = w >> 3;
    int of = w & 7;
    if (i >= clen) return;
    const float4* Ai = (const float4*)(A + (size_t)listP[i] * DFEAT);
    float4 a0 = Ai[lane*4+0], a1 = Ai[lane*4+1], a2 = Ai[lane*4+2], a3 = Ai[lane*4+3];
    for (int j = i + 1 + of; j < clen; j += 8) {
        const float4* Aj = (const float4*)(A + (size_t)listP[j] * DFEAT);
        float d = dot16(a0, a1, a2, a3,
                        Aj[lane*4+0], Aj[lane*4+1], Aj[lane*4+2], Aj[lane*4+3]);
        d = wave_sum(d);
        if (lane == 0) D[(size_t)i * CH + j] = d;
    }
}

// fold new cols into survivors' scv, set flags, chunk meta, per-block counts, build D
__device__ void phase_prepare(const float* __restrict__ A, const float* __restrict__ Y,
                              float* __restrict__ scv, int* __restrict__ flag,
                              const int* __restrict__ listP, int lenL,
                              const int* __restrict__ accT, const float* __restrict__ accK, int nacc,
                              int* __restrict__ chT, float* __restrict__ chB, float* __restrict__ chS,
                              float* __restrict__ D, int* __restrict__ counts,
                              float* SH, int* s_cnt,
                              int bid, int tid, int wv, int lane, int gw)
{
    int clen = min(lenL, CH);
    for (int i = bid * NTHR + tid; i < clen; i += NBLK * NTHR) {
        int t = listP[i];
        chT[i] = t;
        chB[i] = Y[t];
    }
    const int hs = (CH + NBLK - 1) / NBLK;
    int h0 = min(bid * hs, clen), h1 = min(h0 + hs, clen);
    int tailLen = lenL > CH ? lenL - CH : 0;
    int ts2 = (tailLen + NBLK - 1) / NBLK;
    int t0 = CH + min(bid * ts2, tailLen), t1 = min(t0 + ts2, lenL);
    if (tid == 0) *s_cnt = 0;
    __syncthreads();

    for (int jb = 0; jb < nacc; jb += 16) {
        int nj = min(16, nacc - jb);
        if (wv < nj) {
            const float4* Ar = (const float4*)(A + (size_t)accT[jb + wv] * DFEAT);
            float4* S4 = (float4*)SH;
            for (int q = 0; q < 4; ++q) S4[wv * 256 + lane * 4 + q] = Ar[lane * 4 + q];
        }
        __syncthreads();
        const float4* S4 = (const float4*)SH;
        for (int pass = 0; pass < 2; ++pass) {
            int lo = pass ? t0 : h0, hi = pass ? t1 : h1;
            for (int e = lo + wv; e < hi; e += 16) {
                int t = listP[e];
                const float4* At = (const float4*)(A + (size_t)t * DFEAT);
                float4 a0 = At[lane*4+0], a1 = At[lane*4+1], a2 = At[lane*4+2], a3 = At[lane*4+3];
                float cacc = 0.f;
                for (int j = 0; j < nj; ++j) {
                    float d = dot16(a0, a1, a2, a3,
                                    S4[j*256+lane*4+0], S4[j*256+lane*4+1],
                                    S4[j*256+lane*4+2], S4[j*256+lane*4+3]);
                    d = wave_sum(d);
                    float v = accK[jb + j] * d;
                    cacc += v * v;
                }
                if (lane == 0) scv[t] += cacc;
            }
        }
        __syncthreads();
    }

    // epilogue: flags + head meta + tail count
    for (int e = h0 + tid; e < h1; e += NTHR) {
        int t = listP[e];
        float sc = scv[t];
        int alive = (sc <= Y[t]) ? 1 : 0;
        flag[t] = alive;
        chS[e] = alive ? sc : BIGF;
    }
    for (int e = t0 + tid; e < t1; e += NTHR) {
        int t = listP[e];
        float sc = scv[t];
        int alive = (sc <= Y[t]) ? 1 : 0;
        flag[t] = alive;
        if (alive) atomicAdd(s_cnt, 1);
    }
    __syncthreads();
    if (tid == 0) counts[bid] = *s_cnt;

    build_D(A, listP, clen, D, gw, lane);
}

// order-preserving scatter of tail survivors -> listNxt; returns total survivors
__device__ int scatter_and_total(const int* __restrict__ listCur, int lenCur,
                                 const int* __restrict__ flag, const int* __restrict__ counts,
                                 int* __restrict__ listNxt, int bid, int tid, int wv, int lane)
{
    int tailLen = lenCur > CH ? lenCur - CH : 0;
    int ts2 = (tailLen + NBLK - 1) / NBLK;
    int e0 = min(bid * ts2, tailLen), e1 = min(e0 + ts2, tailLen);
    if (wv == 0 && e1 > e0) {
        int dst = 0;
        for (int b = 0; b < bid; ++b) dst += counts[b];
        for (int w0 = e0; w0 < e1; w0 += 64) {
            int idx = w0 + lane;
            int tt = 0, fl = 0;
            if (idx < e1) { tt = listCur[CH + idx]; fl = flag[tt]; }
            unsigned long long mb = __ballot(fl);
            int pos = (int)__popcll(mb & ((1ull << lane) - 1ull));
            if (fl) listNxt[dst + pos] = tt;
            dst += (int)__popcll(mb);
        }
    }
    int tot = 0;
    for (int b = 0; b < NBLK; ++b) tot += counts[b];
    return tot;
}

// block-0 sequential chunk resolution via D
__device__ void resolve_blk0(const float* __restrict__ A, float* __restrict__ Bt,
                             int* __restrict__ ttime,
                             const int* __restrict__ chT, const float* __restrict__ chB,
                             const float* __restrict__ chS, const float* __restrict__ D,
                             int* __restrict__ ctl, int* __restrict__ accT, float* __restrict__ accK,
                             int chunkLen, int tailTotal,
                             float* accL, float* bbL, int* s_red, int* s_imin,
                             int* accTl, float* accKl, int tid, int wv, int lane)
{
    int rc0 = ctl[C_RC];
    if (tid < CH) {
        accL[tid] = (tid < chunkLen) ? chS[tid] : BIGF;
        bbL[tid]  = (tid < chunkLen) ? chB[tid] : -BIGF;
    }
    __syncthreads();
    int rcl = rc0, naccL = 0, shr = 0, tsv = NDATA;
    for (;;) {
        int cand = 0x7FFFFFFF;
        if (tid < chunkLen && accL[tid] <= bbL[tid]) cand = tid;
        cand = wave_min_i(cand);
        if (lane == 0) s_red[wv] = cand;
        __syncthreads();
        if (wv == 0) {
            int v = (lane < 16) ? s_red[lane] : 0x7FFFFFFF;
            v = wave_min_i(v);
            if (lane == 0) *s_imin = v;
        }
        __syncthreads();
        int im = *s_imin;
        if (im == 0x7FFFFFFF) break;
        float sc = accL[im], b = bbL[im];
        float kap = sqrtf(2.f * ETA_F * (b - sc));
        __syncthreads();                    // readers of accL[im] done before writes
        rcl += 1;
        if (tid == 0) { accTl[naccL] = chT[im]; accKl[naccL] = kap; }
        naccL += 1;
        if (tid > im && tid < chunkLen) {
            float dv = D[(size_t)im * CH + tid];
            float v = kap * dv;
            accL[tid] += v * v;
        }
        if (tid <= im && tid < CH) accL[tid] = BIGF;
        if (rcl == TWO_M - 1) { shr = 1; tsv = chT[im]; }
        __syncthreads();
        if (shr) break;
    }
    __syncthreads();
    // append accepted columns
    for (int q = 0; q < naccL; ++q) {
        int colr = rc0 + 1 + q;
        int tq = accTl[q];
        float kq = accKl[q];
        Bt[(size_t)colr * DFEAT + tid] = kq * A[(size_t)tq * DFEAT + tid];
        if (tid == 0) ttime[colr] = tq;
    }
    if (tid < naccL) { accT[tid] = accTl[tid]; accK[tid] = accKl[tid]; }
    if (tid == 0) {
        ctl[C_NACC] = naccL;
        ctl[C_RC]   = rcl;
        ctl[C_SHR]  = shr;
        ctl[C_TS]   = tsv;
        ctl[C_DONE] = (!shr && naccL == 0 && tailTotal == 0) ? 1 : 0;
    }
}

// block-0 FD shrink: Gram -> tournament Jacobi -> sort -> remix Bt
__device__ void jacobi_shrink(float* __restrict__ Bt, int* __restrict__ ctl, float* SH,
                              float* s_rotA, float* s_rotB, int* s_prt,
                              float* s_S, float* s_Ss, int* s_perm, int* s_misc, int tid)
{
    float acc0 = 0.f, acc1 = 0.f, acc2 = 0.f;
    int a0i, b0i, a1i, b1i, a2i, b2i;
    pair_from(tid, a0i, b0i);
    pair_from(tid + 1024, a1i, b1i);
    pair_from((tid < 32) ? (tid + 2048) : 0, a2i, b2i);
    for (int c = 0; c < 4; ++c) {
        __syncthreads();
        for (int q = tid; q < 64 * 64; q += NTHR) {
            int jj = q >> 6, d4 = q & 63;
            float4 v = ((const float4*)(Bt + (size_t)jj * DFEAT + c * 256))[d4];
            TG(jj, d4*4+0) = v.x; TG(jj, d4*4+1) = v.y;
            TG(jj, d4*4+2) = v.z; TG(jj, d4*4+3) = v.w;
        }
        __syncthreads();
        for (int dd = 0; dd < 256; ++dd) {
            acc0 += TG(a0i, dd) * TG(b0i, dd);
            acc1 += TG(a1i, dd) * TG(b1i, dd);
            acc2 += TG(a2i, dd) * TG(b2i, dd);
        }
    }
    SG(0, a0i*64+b0i) = acc0; SG(0, b0i*64+a0i) = acc0;
    SG(0, a1i*64+b1i) = acc1; SG(0, b1i*64+a1i) = acc1;
    if (tid < 32) { SG(0, a2i*64+b2i) = acc2; SG(0, b2i*64+a2i) = acc2; }
    for (int e4 = 0; e4 < 4; ++e4) {
        int e = tid + e4 * 1024;
        SU(0, e) = ((e >> 6) == (e & 63)) ? 1.f : 0.f;
    }
    __syncthreads();

    int cur = 0;
    for (int sw = 0; sw < NSWEEP; ++sw) {
        for (int r = 0; r < 63; ++r) {
            if (tid < 32) {
                int p_, q_;
                if (tid == 0) { p_ = 63; q_ = r; }
                else { p_ = (r + tid) % 63; q_ = (r + 63 - tid) % 63; }
                float gpp = SG(cur, p_*64+p_);
                float gqq = SG(cur, q_*64+q_);
                float gpq = SG(cur, p_*64+q_);
                float cc = 1.f, sn = 0.f;
                if (fabsf(gpq) > 1e-20f) {
                    float tau = (gqq - gpp) / (2.f * gpq);
                    float tt  = (tau >= 0.f ? 1.f : -1.f) / (fabsf(tau) + sqrtf(1.f + tau * tau));
                    cc = 1.f / sqrtf(1.f + tt * tt);
                    sn = tt * cc;
                }
                s_rotA[p_] = cc; s_rotB[p_] = -sn; s_prt[p_] = q_;
                s_rotA[q_] = cc; s_rotB[q_] = sn;  s_prt[q_] = p_;
            }
            __syncthreads();
            float ng[4], nu[4];
            for (int e4 = 0; e4 < 4; ++e4) {
                int e = tid + e4 * 1024;
                int row = e >> 6, col = e & 63;
                int pr = s_prt[row], pc = s_prt[col];
                float ar = s_rotA[row], br = s_rotB[row];
                float ac = s_rotA[col], bc = s_rotB[col];
                ng[e4] = ar*ac*SG(cur, row*64+col) + br*ac*SG(cur, pr*64+col)
                       + ar*bc*SG(cur, row*64+pc)  + br*bc*SG(cur, pr*64+pc);
                nu[e4] = ac*SU(cur, row*64+col) + bc*SU(cur, row*64+pc);
            }
            for (int e4 = 0; e4 < 4; ++e4) {
                int e = tid + e4 * 1024;
                SG(cur ^ 1, e) = ng[e4];
                SU(cur ^ 1, e) = nu[e4];
            }
            __syncthreads();
            cur ^= 1;
        }
    }

    if (tid < 64) {
        float lam = SG(cur, tid*64+tid);
        if (lam <= THRES_F) lam = 0.f;
        s_S[tid] = lam;
    }
    __syncthreads();
    if (tid < 64) {
        float my = s_S[tid];
        int rank = 0;
        for (int i = 0; i < 64; ++i) {
            float o = s_S[i];
            rank += ((o > my) || (o == my && i < tid)) ? 1 : 0;
        }
        s_perm[rank] = tid;
        s_Ss[rank]   = my;
    }
    __syncthreads();
    if (tid == 0) {
        int nz = 0;
        for (int i = 0; i < 64; ++i) nz += (s_Ss[i] > 0.f) ? 1 : 0;
        s_misc[0] = nz;
        s_misc[1] = (nz >= MM) ? 1 : 0;
    }
    __syncthreads();
    const int nnz = s_misc[0];
    const int ge  = s_misc[1];
    const float S32 = s_Ss[MM];

    for (int e4 = 0; e4 < 4; ++e4) {
        int e = tid + e4 * 1024;
        int kk = e >> 6, jn = e & 63;
        float Sj = s_Ss[jn];
        float f;
        if (ge) f = (jn < MM - 1 && Sj > 0.f) ? sqrtf(fmaxf(Sj - S32, 0.f) / Sj) : 0.f;
        else    f = (jn < nnz) ? 1.f : 0.f;
        SG(0, kk*64+jn) = SU(cur, kk*64 + s_perm[jn]) * f;
    }
    __syncthreads();

    for (int c = 0; c < 4; ++c) {
        __syncthreads();
        for (int q = tid; q < 64 * 64; q += NTHR) {
            int jj = q >> 6, d4 = q & 63;
            float4 v = ((const float4*)(Bt + (size_t)jj * DFEAT + c * 256))[d4];
            TG(jj, d4*4+0) = v.x; TG(jj, d4*4+1) = v.y;
            TG(jj, d4*4+2) = v.z; TG(jj, d4*4+3) = v.w;
        }
        __syncthreads();
        for (int q = tid; q < 64 * 256; q += NTHR) {
            int dd = q & 255, jn = q >> 8;
            float sum = 0.f;
            for (int kk = 0; kk < 64; ++kk)
                sum += TG(kk, dd) * SG(0, kk*64+jn);
            Bt[(size_t)jn * DFEAT + c * 256 + dd] = sum;
        }
    }
    __syncthreads();
    if (tid == 0) {
        int rcn = ge ? (MM - 1) : nnz;
        ctl[C_RCA] = rcn;
        ctl[C_RC]  = rcn;
    }
}

// post-shrink: scv/base/flag for all rows t > ts, Bt staged in LDS halves, 2 rows/wave
__device__ void recompute_rows(const float* __restrict__ A, const float* __restrict__ Y,
                               const float* __restrict__ Bt,
                               float* __restrict__ scv, float* __restrict__ base,
                               int* __restrict__ flag, int ts,
                               float* SH, int tid, int wv, int lane, int gw)
{
    int nrows = NDATA - 1 - ts;
    int npair = (nrows + 1) >> 1;
    for (int h = 0; h < 2; ++h) {
        {
            const float4* B4 = (const float4*)Bt;
            float4* S4 = (float4*)SH;
            for (int q = 0; q < 4; ++q) {
                S4[wv * 256 + lane*4 + q]        = B4[(size_t)(h*32 + wv) * 256 + lane*4 + q];
                S4[(wv+16) * 256 + lane*4 + q]   = B4[(size_t)(h*32 + wv + 16) * 256 + lane*4 + q];
            }
        }
        __syncthreads();
        const float4* S4 = (const float4*)SH;
        for (int p = gw; p < npair; p += NW) {
            int tA = ts + 1 + 2*p;
            int tB = tA + 1;
            bool hasB = tB < NDATA;
            const float4* Aa = (const float4*)(A + (size_t)tA * DFEAT);
            float4 x0 = Aa[lane*4+0], x1 = Aa[lane*4+1], x2 = Aa[lane*4+2], x3 = Aa[lane*4+3];
            float4 y0 = make_float4(0,0,0,0), y1 = y0, y2 = y0, y3 = y0;
            if (hasB) {
                const float4* Ab = (const float4*)(A + (size_t)tB * DFEAT);
                y0 = Ab[lane*4+0]; y1 = Ab[lane*4+1]; y2 = Ab[lane*4+2]; y3 = Ab[lane*4+3];
            }
            float s1 = 0.f, s2 = 0.f;
            for (int j = 0; j < 32; ++j) {
                float4 b0 = S4[j*256+lane*4+0], b1 = S4[j*256+lane*4+1],
                       b2 = S4[j*256+lane*4+2], b3 = S4[j*256+lane*4+3];
                float d1 = dot16(x0,x1,x2,x3,b0,b1,b2,b3);
                d1 = wave_sum(d1);
                s1 += d1 * d1;
                float d2 = dot16(y0,y1,y2,y3,b0,b1,b2,b3);
                d2 = wave_sum(d2);
                s2 += d2 * d2;
            }
            if (lane == 0) {
                if (h == 0) {
                    scv[tA] = s1;
                    if (hasB) scv[tB] = s2;
                } else {
                    float f1 = scv[tA] + s1;
                    scv[tA] = f1; base[tA] = f1; flag[tA] = (f1 <= Y[tA]) ? 1 : 0;
                    if (hasB) {
                        float f2 = scv[tB] + s2;
                        scv[tB] = f2; base[tB] = f2; flag[tB] = (f2 <= Y[tB]) ? 1 : 0;
                    }
                }
            }
        }
        __syncthreads();
    }
}

__global__ __launch_bounds__(NTHR, 4)
void sftrl_v3(const float* __restrict__ A, const float* __restrict__ Y,
              float* __restrict__ out, char* __restrict__ ws)
{
    cg::grid_group grid = cg::this_grid();
    const int tid = threadIdx.x, lane = tid & 63, wv = tid >> 6, bid = blockIdx.x;
    const int gw = bid * 16 + wv;

    int*   ctl    = (int*)(ws + O_CTL);
    int*   counts = (int*)(ws + O_CNT);
    int*   accT   = (int*)(ws + O_ACCT);
    float* accK   = (float*)(ws + O_ACCK);
    int*   ttime  = (int*)(ws + O_TTIME);
    float* Bt     = (float*)(ws + O_BT);
    float* base   = (float*)(ws + O_BASE);
    float* scv    = (float*)(ws + O_SCV);
    int*   flag   = (int*)(ws + O_FLAG);
    int*   cl0    = (int*)(ws + O_CL0);
    int*   LA     = (int*)(ws + O_LA);
    int*   LB     = (int*)(ws + O_LB);
    int*   chT    = (int*)(ws + O_CHT);
    float* chB    = (float*)(ws + O_CHB);
    float* chS    = (float*)(ws + O_CHS);
    float* D      = (float*)(ws + O_D);

    __shared__ float SH[32832];
    __shared__ float s_rotA[64], s_rotB[64];
    __shared__ int   s_prt[64];
    __shared__ float s_S[64], s_Ss[64];
    __shared__ int   s_perm[64], s_misc[2];
    __shared__ float accL[CH], bbL[CH];
    __shared__ int   s_red[16];
    __shared__ int   s_imin, s_cnt;
    __shared__ int   accTl[64];
    __shared__ float accKl[64];

    // ---------------- P0a: init + per-block candidate counts ----------------
    const int rb = (NDATA + NBLK - 1) / NBLK;
    int r0 = min(bid * rb, NDATA), r1 = min(r0 + rb, NDATA);
    if (tid == 0) s_cnt = 0;
    __syncthreads();
    for (int t = r0 + tid; t < r1; t += NTHR) {
        base[t] = 0.f; scv[t] = 0.f;
        int f = (0.f <= Y[t]) ? 1 : 0;
        flag[t] = f;
        if (f) atomicAdd(&s_cnt, 1);
    }
    for (int i = bid * NTHR + tid; i < TWO_M * DFEAT; i += NBLK * NTHR) Bt[i] = 0.f;
    if (bid == 0 && tid < 16) ctl[tid] = 0;
    __syncthreads();
    if (tid == 0) counts[bid] = s_cnt;
    __threadfence();
    grid.sync();

    // ---------------- P0b: scatter cl0 (sorted) ----------------
    {
        int dst = 0;
        for (int b = 0; b < bid; ++b) dst += counts[b];
        if (wv == 0) {
            for (int w0 = r0; w0 < r1; w0 += 64) {
                int t = w0 + lane;
                int fl = (t < r1) ? flag[t] : 0;
                unsigned long long mb = __ballot(fl);
                int pos = (int)__popcll(mb & ((1ull << lane) - 1ull));
                if (fl) cl0[dst + pos] = t;
                dst += (int)__popcll(mb);
            }
        }
    }
    int ncand = 0;
    for (int b = 0; b < NBLK; ++b) ncand += counts[b];
    __threadfence();
    grid.sync();

    // ---------------- P0c: first chunk prep ----------------
    int* listCur = cl0;
    int  lenCur  = ncand;
    phase_prepare(A, Y, scv, flag, listCur, lenCur, accT, accK, 0,
                  chT, chB, chS, D, counts, SH, &s_cnt, bid, tid, wv, lane, gw);
    __threadfence();
    grid.sync();

    int fin_hi = -1, seg_lo = 1;

    for (;;) {
        int chunkLen = min(lenCur, CH);
        int* listNxt = (listCur == LA) ? LB : LA;

        // ---------------- P1: scatter || resolve ----------------
        int tailTotal = scatter_and_total(listCur, lenCur, flag, counts, listNxt,
                                          bid, tid, wv, lane);
        if (bid == 0)
            resolve_blk0(A, Bt, ttime, chT, chB, chS, D, ctl, accT, accK,
                         chunkLen, tailTotal, accL, bbL, s_red, &s_imin,
                         accTl, accKl, tid, wv, lane);
        __threadfence();
        grid.sync();

        int nacc = ctl[C_NACC], rc = ctl[C_RC], shr = ctl[C_SHR], done = ctl[C_DONE];
        if (done) {
            finalize_range(A, base, Bt, ttime, out, fin_hi + 1, NDATA - 1, seg_lo, rc, gw, lane);
            return;
        }
        if (shr) {
            int ts = ctl[C_TS];
            // ---- P2s: finalize the closing segment with OLD Bt ----
            finalize_range(A, base, Bt, ttime, out, fin_hi + 1, ts, seg_lo, rc - 1, gw, lane);
            __threadfence();
            grid.sync();
            // ---- P3s: blk0 jacobi || others pre-build post-shrink chunk ----
            int cstart = lbound(cl0, ncand, ts);
            int clen2 = min(ncand - cstart, CH);
            if (bid == 0) {
                jacobi_shrink(Bt, ctl, SH, s_rotA, s_rotB, s_prt, s_S, s_Ss, s_perm, s_misc, tid);
            } else {
                if (bid == 1) {
                    for (int i = tid; i < clen2; i += NTHR) {
                        int t = cl0[cstart + i];
                        chT[i] = t; chB[i] = Y[t];
                    }
                }
                build_D(A, cl0 + cstart, clen2, D, (bid - 1) * 16 + wv, lane);
            }
            __threadfence();
            grid.sync();
            int rcn = ctl[C_RCA];
            seg_lo = rcn + 1; fin_hi = ts;
            // ---- P4s: recompute scv/base/flag for t > ts with NEW Bt ----
            recompute_rows(A, Y, Bt, scv, base, flag, ts, SH, tid, wv, lane, gw);
            __threadfence();
            grid.sync();
            // ---- P4s2: chunk meta + tail counts ----
            listCur = cl0 + cstart; lenCur = ncand - cstart;
            for (int i = bid * NTHR + tid; i < clen2; i += NBLK * NTHR) {
                int t = chT[i];
                chS[i] = flag[t] ? scv[t] : BIGF;
            }
            {
                int tailLen = lenCur > CH ? lenCur - CH : 0;
                int ts2 = (tailLen + NBLK - 1) / NBLK;
                int e0 = min(bid * ts2, tailLen), e1 = min(e0 + ts2, tailLen);
                if (tid == 0) s_cnt = 0;
                __syncthreads();
                for (int e = e0 + tid; e < e1; e += NTHR) {
                    int t = listCur[CH + e];
                    if (flag[t]) atomicAdd(&s_cnt, 1);
                }
                __syncthreads();
                if (tid == 0) counts[bid] = s_cnt;
            }
            __threadfence();
            grid.sync();
            continue;
        }
        // ---------------- P2: fold + compact-count + next chunk prep ----------------
        int lenNxt = tailTotal;
        phase_prepare(A, Y, scv, flag, listNxt, lenNxt, accT, accK, nacc,
                      chT, chB, chS, D, counts, SH, &s_cnt, bid, tid, wv, lane, gw);
        __threadfence();
        grid.sync();
        listCur = listNxt; lenCur = lenNxt;
    }
}

extern "C" void kernel_launch(void* const* d_in, const int* in_sizes, int n_in,
                              void* d_out, int out_size, void* d_ws, size_t ws_size,
                              hipStream_t stream) {
    (void)in_sizes; (void)n_in; (void)ws_size; (void)out_size;
    const float* A = (const float*)d_in[0];
    const float* Y = (const float*)d_in[1];
    float* out = (float*)d_out;
    char* ws = (char*)d_ws;
    void* kargs[] = { (void*)&A, (void*)&Y, (void*)&out, (void*)&ws };
    hipLaunchCooperativeKernel((void*)sftrl_v3, dim3(NBLK), dim3(NTHR), kargs, 0, stream);
}